// Round 6
// baseline (203.314 us; speedup 1.0000x reference)
//
#include <hip/hip_runtime.h>

#define NBOX    25200
#define NQ4     6300           // NBOX/4
#define NBATCH  16
#define NCLS    80
#define MAXDET  100
#define NBUCKET 1024
#define CAP     13824          // all candidates: mean 12600 +15 sigma
#define SCORE_THR 0.5f
#define IOU_THR   0.5f
#define NGROUP  16             // 64 buckets per group
#define LAZY_BKT 896           // buckets >= this (groups 0-1) scattered eagerly
#define STAGECAP 1152          // per-group stage: mean 787 +13 sigma

// Exact replication of reference fp32 arithmetic: no FMA contraction.
__device__ __forceinline__ void mk_corners(float x, float y, float w, float h,
                                           float& x1, float& y1, float& x2, float& y2) {
#pragma clang fp contract(off)
    float hw = w * 0.5f;
    float hh = h * 0.5f;
    x1 = x - hw; y1 = y - hh; x2 = x + hw; y2 = y + hh;
}

__device__ __forceinline__ float areaf(float x1, float y1, float x2, float y2) {
#pragma clang fp contract(off)
    return (x2 - x1) * (y2 - y1);
}

__device__ __forceinline__ bool iou_gt(float kx1, float ky1, float kx2, float ky2, float ka,
                                       float cx1, float cy1, float cx2, float cy2, float ca) {
#pragma clang fp contract(off)
    float lx = fmaxf(kx1, cx1);
    float ly = fmaxf(ky1, cy1);
    float rx = fminf(kx2, cx2);
    float ry = fminf(ky2, cy2);
    float w  = fmaxf(rx - lx, 0.0f);
    float h  = fmaxf(ry - ly, 0.0f);
    float inter = w * h;
    float denom = ka + ca - inter + 1e-9f;
    return (inter / denom) > IOU_THR;
}

__device__ __forceinline__ float readlane_f(float v, int j) {
    return __uint_as_float((unsigned)__builtin_amdgcn_readlane((int)__float_as_uint(v), j));
}

__device__ __forceinline__ unsigned score_key(float s) {
    // score in [0.5, 1): ekey in [0, 2^23); bkt = top 10 bits, el = low 13
    return __float_as_uint(s) - 0x3F000000u;
}

__global__ __launch_bounds__(1024)
void nms_kernel(const float* __restrict__ boxes_xywh,
                const float* __restrict__ objectness,
                const float* __restrict__ class_prob,
                float* __restrict__ out) {
    __shared__ unsigned s_hist[NBUCKET];
    __shared__ unsigned s_start[NBUCKET];
    __shared__ unsigned s_a[CAP];              // bucketed keys; sorted in place per bucket
    __shared__ float4   s_cc[2][STAGECAP];     // staged corners (double-buffered by group)
    __shared__ float    s_cs[2][STAGECAP];     // staged exact score
    __shared__ unsigned s_ci[2][STAGECAP];     // staged original index
    __shared__ float4   s_kbox[MAXDET];
    __shared__ unsigned s_kept_idx[MAXDET];
    __shared__ unsigned s_wsum[16];
    __shared__ unsigned s_woff[16];
    __shared__ int      s_count;

    const int b = blockIdx.x;
    const int t = threadIdx.x;
    const int w = t >> 6;
    const int l = t & 63;
    const float* obj = objectness + (size_t)b * NBOX;
    const float* bx  = boxes_xywh + (size_t)b * NBOX * 4;

    // ---- Phase 0: register-cache all objectness (7 float4 per thread) ----
    float4 r[7];
#pragma unroll
    for (int i = 0; i < 7; ++i) {
        int n4 = t + (i << 10);
        if (n4 < NQ4) r[i] = *(const float4*)(obj + n4 * 4);
    }

    // ---- Phase 1: histogram over top-10 mantissa bits ----
    s_hist[t] = 0u;
    __syncthreads();
#pragma unroll
    for (int i = 0; i < 7; ++i) {
        int n4 = t + (i << 10);
        if (n4 < NQ4) {
            float sv[4] = {r[i].x, r[i].y, r[i].z, r[i].w};
#pragma unroll
            for (int u = 0; u < 4; ++u) {
                if (sv[u] >= SCORE_THR) {
                    unsigned bkt = score_key(sv[u]) >> 13;
                    if (bkt > 1023u) bkt = 1023u;
                    atomicAdd(&s_hist[bkt], 1u);
                }
            }
        }
    }
    __syncthreads();

    // ---- Phase 2: reverse exclusive scan via wave scans ----
    {
        unsigned f = s_hist[1023 - t];
        unsigned v = f;
#pragma unroll
        for (int off = 1; off < 64; off <<= 1) {
            unsigned u = (unsigned)__shfl_up((int)v, off);
            if (l >= off) v += u;
        }
        if (l == 63) s_wsum[w] = v;
        __syncthreads();
        if (t < 64) {
            unsigned x = (t < 16) ? s_wsum[t] : 0u;
            unsigned y = x;
#pragma unroll
            for (int off = 1; off < 16; off <<= 1) {
                unsigned u = (unsigned)__shfl_up((int)y, off);
                if (t >= off) y += u;
            }
            if (t < 16) s_woff[t] = y - x;
        }
        __syncthreads();
        s_start[1023 - t] = v - f + s_woff[w];
    }
    if (t == 0) s_count = 0;
    __syncthreads();

    // ---- Phase 3: LAZY scatter — only groups 0-1 (buckets >= LAZY_BKT) ----
#pragma unroll
    for (int i = 0; i < 7; ++i) {
        int n4 = t + (i << 10);
        if (n4 < NQ4) {
            float sv[4] = {r[i].x, r[i].y, r[i].z, r[i].w};
#pragma unroll
            for (int u = 0; u < 4; ++u) {
                if (sv[u] >= SCORE_THR) {
                    unsigned ekey = score_key(sv[u]);
                    unsigned bkt  = ekey >> 13;
                    if (bkt > 1023u) bkt = 1023u;
                    if (bkt >= LAZY_BKT) {
                        int n = n4 * 4 + u;
                        unsigned pos = atomicAdd(&s_start[bkt], 1u);
                        if (pos < CAP)
                            s_a[pos] = ((ekey & 0x1FFFu) << 18) | (0x3FFFFu - (unsigned)n);
                    }
                }
            }
        }
    }
    __syncthreads();

    // per-bucket in-place rank sort + stage (corners/score/idx) — one wave per call
    auto sort_stage = [&](int bkt, unsigned gbase, int buf) {
        unsigned h = s_hist[bkt];
        if (h == 0u) return;
        unsigned end = s_start[bkt];        // post-scatter: start + count
        unsigned hi  = (end > CAP) ? CAP : end;
        unsigned lo  = (end >= h) ? end - h : 0u;
        if (lo > hi) lo = hi;
        unsigned sz = hi - lo;
        if (sz == 0u) return;
        if (sz <= 64u) {
            unsigned v = (l < (int)sz) ? s_a[lo + (unsigned)l] : 0u;
            int rank = 0;
            for (unsigned j = 0; j < sz; ++j)
                rank += ((unsigned)__shfl((int)v, (int)j) > v) ? 1 : 0;
            if (l < (int)sz) {
                s_a[lo + (unsigned)rank] = v;              // in-place: regs hold inputs
                unsigned spos = lo + (unsigned)rank - gbase;
                if (spos < STAGECAP) {
                    unsigned idx = 0x3FFFFu - (v & 0x3FFFFu);
                    float4 q = *(const float4*)(bx + (size_t)idx * 4);
                    float x1, y1, x2, y2;
                    mk_corners(q.x, q.y, q.z, q.w, x1, y1, x2, y2);
                    s_cc[buf][spos] = make_float4(x1, y1, x2, y2);
                    s_cs[buf][spos] = __uint_as_float(0x3F000000u +
                                        (((unsigned)bkt << 13) | (v >> 18)));
                    s_ci[buf][spos] = idx;
                }
            }
        } else {
            // generic path (bucket > 64: astronomically rare) — up to 320 entries
            if (sz > 320u) sz = 320u;
            unsigned v[5]; int rk[5];
            int nch = (int)((sz + 63u) >> 6);
#pragma unroll
            for (int c = 0; c < 5; ++c) {
                unsigned p = (unsigned)(c * 64 + l);
                v[c] = (c < nch && p < sz) ? s_a[lo + p] : 0u;
                rk[c] = 0;
            }
            for (int c2 = 0; c2 < nch; ++c2) {
                for (int j = 0; j < 64; ++j) {
                    unsigned o = (unsigned)__shfl((int)v[c2], j);
                    bool val = (unsigned)(c2 * 64 + j) < sz;
#pragma unroll
                    for (int c = 0; c < 5; ++c)
                        rk[c] += (val && o > v[c]) ? 1 : 0;
                }
            }
#pragma unroll
            for (int c = 0; c < 5; ++c) {
                unsigned p = (unsigned)(c * 64 + l);
                if (c < nch && p < sz) {
                    s_a[lo + (unsigned)rk[c]] = v[c];
                    unsigned spos = lo + (unsigned)rk[c] - gbase;
                    if (spos < STAGECAP) {
                        unsigned idx = 0x3FFFFu - (v[c] & 0x3FFFFu);
                        float4 q = *(const float4*)(bx + (size_t)idx * 4);
                        float x1, y1, x2, y2;
                        mk_corners(q.x, q.y, q.z, q.w, x1, y1, x2, y2);
                        s_cc[buf][spos] = make_float4(x1, y1, x2, y2);
                        s_cs[buf][spos] = __uint_as_float(0x3F000000u +
                                            (((unsigned)bkt << 13) | (v[c] >> 18)));
                        s_ci[buf][spos] = idx;
                    }
                }
            }
        }
    };

    // ---- pre-sort + stage group 0 (buckets 960..1023) with all 16 waves ----
    for (int bkt = 960 + w; bkt <= 1023; bkt += 16) sort_stage(bkt, 0u, 0);
    __syncthreads();

    // ---- Pipelined group loop: wave 0 greedy on g; waves 1-15 stage g+1 ----
    int count = 0;
    int nscat = 2;   // groups scattered so far (uniform)
    for (int g = 0; g < NGROUP; ++g) {
        const int BH = 1023 - (g << 6);
        const int BL = BH - 63;

        if (g >= nscat) {
            // RARE fallback: scatter all remaining buckets (< LAZY_BKT) from global
            for (int n4 = t; n4 < NQ4; n4 += 1024) {
                float4 s4 = *(const float4*)(obj + n4 * 4);
                float sv[4] = {s4.x, s4.y, s4.z, s4.w};
#pragma unroll
                for (int u = 0; u < 4; ++u) {
                    if (sv[u] >= SCORE_THR) {
                        unsigned ekey = score_key(sv[u]);
                        unsigned bkt  = ekey >> 13;
                        if (bkt > 1023u) bkt = 1023u;
                        if (bkt < LAZY_BKT) {
                            int n = n4 * 4 + u;
                            unsigned pos = atomicAdd(&s_start[bkt], 1u);
                            if (pos < CAP)
                                s_a[pos] = ((ekey & 0x1FFFu) << 18) | (0x3FFFFu - (unsigned)n);
                        }
                    }
                }
            }
            __syncthreads();
            nscat = NGROUP;
            unsigned gb = s_start[BH + 1];      // end of group g-1 = base of group g
            if (gb > CAP) gb = CAP;
            for (int bkt = BL + w; bkt <= BH; bkt += 16) sort_stage(bkt, gb, g & 1);
            __syncthreads();
        }

        if (w == 0) {
            unsigned glo = (g == 0) ? 0u : s_start[BH + 1];
            unsigned ghi = s_start[BL];
            if (glo > CAP) glo = CAP;
            if (ghi > CAP) ghi = CAP;
            const int buf = g & 1;
            const int gsz = (int)(ghi - glo);

            for (int lb = 0; lb < gsz && count < MAXDET; lb += 64) {
                int m = gsz - lb; if (m > 64) m = 64;
                const int sp = lb + l;
                const bool valid  = l < m;
                const bool staged = sp < STAGECAP;
                float cx1 = 0.f, cy1 = 0.f, cx2 = 0.f, cy2 = 0.f;
                if (valid) {
                    if (staged) {
                        float4 cc = s_cc[buf][sp];
                        cx1 = cc.x; cy1 = cc.y; cx2 = cc.z; cy2 = cc.w;
                    } else {   // stage overflow (rare): gather from global via sorted keys
                        unsigned v = s_a[glo + (unsigned)sp];
                        unsigned idx = 0x3FFFFu - (v & 0x3FFFFu);
                        float4 q = *(const float4*)(bx + (size_t)idx * 4);
                        mk_corners(q.x, q.y, q.z, q.w, cx1, cy1, cx2, cy2);
                    }
                }
                float ca = areaf(cx1, cy1, cx2, cy2);

                // vs-kept pre-filter: batches of 4 independent LDS loads
                bool sup = !valid;
                int k = 0;
                for (; k + 4 <= count; k += 4) {
                    float4 kb0 = s_kbox[k],     kb1 = s_kbox[k + 1];
                    float4 kb2 = s_kbox[k + 2], kb3 = s_kbox[k + 3];
                    sup = sup | iou_gt(kb0.x, kb0.y, kb0.z, kb0.w,
                                       areaf(kb0.x, kb0.y, kb0.z, kb0.w), cx1, cy1, cx2, cy2, ca);
                    sup = sup | iou_gt(kb1.x, kb1.y, kb1.z, kb1.w,
                                       areaf(kb1.x, kb1.y, kb1.z, kb1.w), cx1, cy1, cx2, cy2, ca);
                    sup = sup | iou_gt(kb2.x, kb2.y, kb2.z, kb2.w,
                                       areaf(kb2.x, kb2.y, kb2.z, kb2.w), cx1, cy1, cx2, cy2, ca);
                    sup = sup | iou_gt(kb3.x, kb3.y, kb3.z, kb3.w,
                                       areaf(kb3.x, kb3.y, kb3.z, kb3.w), cx1, cy1, cx2, cy2, ca);
                }
                for (; k < count; ++k) {
                    float4 kb = s_kbox[k];
                    sup = sup | iou_gt(kb.x, kb.y, kb.z, kb.w,
                                       areaf(kb.x, kb.y, kb.z, kb.w), cx1, cy1, cx2, cy2, ca);
                }
                unsigned long long act = __ballot(!sup);

                // serial accept loop: v_readlane broadcasts, writes deferred
                unsigned long long accmask = 0ull;
                const int cbase = count;
                while (act != 0ull && count < MAXDET) {
                    int j = (int)__builtin_ctzll(act);
                    accmask |= 1ull << j;
                    float bx1 = readlane_f(cx1, j), by1 = readlane_f(cy1, j);
                    float bx2 = readlane_f(cx2, j), by2 = readlane_f(cy2, j);
                    float bar = readlane_f(ca, j);
                    bool su = iou_gt(bx1, by1, bx2, by2, bar, cx1, cy1, cx2, cy2, ca);
                    ++count;
                    act &= ~(1ull << j);
                    act &= ~__ballot(su);
                }

                // parallel deferred writeback of this chunk's accepts
                if (accmask & (1ull << l)) {
                    int slot = cbase + (int)__popcll(accmask & ((1ull << l) - 1ull));
                    unsigned cidx; float csc;
                    if (staged) {
                        cidx = s_ci[buf][sp];
                        csc  = s_cs[buf][sp];
                    } else {
                        unsigned v = s_a[glo + (unsigned)sp];
                        cidx = 0x3FFFFu - (v & 0x3FFFFu);
                        csc  = obj[cidx];
                    }
                    s_kbox[slot] = make_float4(cx1, cy1, cx2, cy2);
                    s_kept_idx[slot] = cidx;
                    float* ob = out + ((size_t)b * MAXDET + slot) * 4;
                    ob[0] = cx1; ob[1] = cy1; ob[2] = cx2; ob[3] = cy2;
                    out[NBATCH * MAXDET * 4 + b * MAXDET + slot] = csc;
                }
                __asm__ volatile("s_waitcnt lgkmcnt(0)" ::: "memory");
            }
            if (l == 0) s_count = count;
        } else if (g + 1 < NGROUP && g + 1 < nscat) {
            // waves 1-15: sort + stage next group (base = end of group g)
            const int BH2 = BH - 64, BL2 = BH2 - 63;
            unsigned gb = s_start[BL];
            if (gb > CAP) gb = CAP;
            for (int bkt = BL2 + (w - 1); bkt <= BH2; bkt += 15)
                sort_stage(bkt, gb, (g + 1) & 1);
        }
        __syncthreads();
        if (s_count >= MAXDET) break;
    }

    // ---- Epilogue: gather class rows, zero only tails, write count ----
    const int cf = s_count;
    for (int e = t; e < MAXDET * 4; e += 1024) {
        if ((e >> 2) >= cf) out[(size_t)b * MAXDET * 4 + e] = 0.0f;
    }
    for (int i = t; i < MAXDET; i += 1024) {
        if (i >= cf) out[NBATCH * MAXDET * 4 + b * MAXDET + i] = 0.0f;
    }
    const float* cp = class_prob + (size_t)b * NBOX * NCLS;
    float* oc = out + NBATCH * MAXDET * 5 + (size_t)b * MAXDET * NCLS;
    for (int e = t; e < cf * NCLS; e += 1024) {
        int i = e / NCLS;
        int c = e - i * NCLS;
        oc[e] = cp[(size_t)s_kept_idx[i] * NCLS + c];
    }
    for (int e = t + cf * NCLS; e < MAXDET * NCLS; e += 1024) oc[e] = 0.0f;
    if (t == 0)
        out[NBATCH * MAXDET * 5 + NBATCH * MAXDET * NCLS + b] = (float)cf;
}

extern "C" void kernel_launch(void* const* d_in, const int* in_sizes, int n_in,
                              void* d_out, int out_size, void* d_ws, size_t ws_size,
                              hipStream_t stream) {
    const float* boxes = (const float*)d_in[0];
    const float* objn  = (const float*)d_in[1];
    const float* clsp  = (const float*)d_in[2];
    float* out = (float*)d_out;
    nms_kernel<<<dim3(NBATCH), dim3(1024), 0, stream>>>(boxes, objn, clsp, out);
}

// Round 7
// 196.666 us; speedup vs baseline: 1.0338x; 1.0338x over previous
//
#include <hip/hip_runtime.h>

#define NBOX    25200
#define NQ4     6300           // NBOX/4
#define NBATCH  16
#define NCLS    80
#define MAXDET  100
#define NBUCKET 1024
#define CAP     13824          // expected candidates ~12600, +15 sigma
#define SCORE_THR 0.5f
#define IOU_THR   0.5f
#define NGROUP  16             // 64 buckets per group
#define LAZY_BKT 896           // buckets >= this (groups 0-1) scattered eagerly

// Exact replication of reference fp32 arithmetic: no FMA contraction.
__device__ __forceinline__ void mk_corners(float x, float y, float w, float h,
                                           float& x1, float& y1, float& x2, float& y2) {
#pragma clang fp contract(off)
    float hw = w * 0.5f;
    float hh = h * 0.5f;
    x1 = x - hw; y1 = y - hh; x2 = x + hw; y2 = y + hh;
}

__device__ __forceinline__ float areaf(float x1, float y1, float x2, float y2) {
#pragma clang fp contract(off)
    return (x2 - x1) * (y2 - y1);
}

__device__ __forceinline__ bool iou_gt(float kx1, float ky1, float kx2, float ky2, float ka,
                                       float cx1, float cy1, float cx2, float cy2, float ca) {
#pragma clang fp contract(off)
    float lx = fmaxf(kx1, cx1);
    float ly = fmaxf(ky1, cy1);
    float rx = fminf(kx2, cx2);
    float ry = fminf(ky2, cy2);
    float w  = fmaxf(rx - lx, 0.0f);
    float h  = fmaxf(ry - ly, 0.0f);
    float inter = w * h;
    float denom = ka + ca - inter + 1e-9f;
    return (inter / denom) > IOU_THR;
}

__device__ __forceinline__ float readlane_f(float v, int j) {
    return __uint_as_float((unsigned)__builtin_amdgcn_readlane((int)__float_as_uint(v), j));
}

__device__ __forceinline__ unsigned score_key(float s) {
    // score in [0.5, 1): ekey in [0, 2^23); bkt = top 10 bits, el = low 13
    return __float_as_uint(s) - 0x3F000000u;
}

__global__ __launch_bounds__(1024)
void nms_kernel(const float* __restrict__ boxes_xywh,
                const float* __restrict__ objectness,
                const float* __restrict__ class_prob,
                float* __restrict__ out) {
    __shared__ unsigned s_hist[NBUCKET];
    __shared__ unsigned s_start[NBUCKET];
    __shared__ unsigned s_a[CAP];          // scattered (bucketed, unsorted-in-bucket)
    __shared__ unsigned s_b[CAP];          // sorted descending (filled lazily)
    __shared__ float4   s_kbox[MAXDET];
    __shared__ unsigned s_kept_idx[MAXDET];
    __shared__ unsigned s_wsum[16];
    __shared__ unsigned s_woff[16];
    __shared__ int      s_count;

    const int b = blockIdx.x;
    const int t = threadIdx.x;
    const int w = t >> 6;
    const int l = t & 63;
    const float* obj = objectness + (size_t)b * NBOX;
    const float* bx  = boxes_xywh + (size_t)b * NBOX * 4;

    // ---- Phase 0: register-cache all objectness (7 float4 per thread) ----
    float4 r[7];
#pragma unroll
    for (int i = 0; i < 7; ++i) {
        int n4 = t + (i << 10);
        if (n4 < NQ4) r[i] = *(const float4*)(obj + n4 * 4);
    }

    // ---- Phase 1: histogram over top-10 mantissa bits ----
    s_hist[t] = 0u;
    __syncthreads();
#pragma unroll
    for (int i = 0; i < 7; ++i) {
        int n4 = t + (i << 10);
        if (n4 < NQ4) {
            float sv[4] = {r[i].x, r[i].y, r[i].z, r[i].w};
#pragma unroll
            for (int u = 0; u < 4; ++u) {
                if (sv[u] >= SCORE_THR) {
                    unsigned bkt = score_key(sv[u]) >> 13;
                    if (bkt > 1023u) bkt = 1023u;
                    atomicAdd(&s_hist[bkt], 1u);
                }
            }
        }
    }
    __syncthreads();

    // ---- Phase 2: reverse exclusive scan via wave scans ----
    {
        unsigned f = s_hist[1023 - t];
        unsigned v = f;
#pragma unroll
        for (int off = 1; off < 64; off <<= 1) {
            unsigned u = (unsigned)__shfl_up((int)v, off);
            if (l >= off) v += u;
        }
        if (l == 63) s_wsum[w] = v;
        __syncthreads();
        if (t < 64) {
            unsigned x = (t < 16) ? s_wsum[t] : 0u;
            unsigned y = x;
#pragma unroll
            for (int off = 1; off < 16; off <<= 1) {
                unsigned u = (unsigned)__shfl_up((int)y, off);
                if (t >= off) y += u;
            }
            if (t < 16) s_woff[t] = y - x;
        }
        __syncthreads();
        s_start[1023 - t] = v - f + s_woff[w];
    }
    if (t == 0) s_count = 0;
    __syncthreads();

    // ---- Phase 3: LAZY scatter — only groups 0-1 (buckets >= LAZY_BKT) ----
#pragma unroll
    for (int i = 0; i < 7; ++i) {
        int n4 = t + (i << 10);
        if (n4 < NQ4) {
            float sv[4] = {r[i].x, r[i].y, r[i].z, r[i].w};
#pragma unroll
            for (int u = 0; u < 4; ++u) {
                if (sv[u] >= SCORE_THR) {
                    unsigned ekey = score_key(sv[u]);
                    unsigned bkt  = ekey >> 13;
                    if (bkt > 1023u) bkt = 1023u;
                    if (bkt >= LAZY_BKT) {
                        int n = n4 * 4 + u;
                        unsigned pos = atomicAdd(&s_start[bkt], 1u);
                        if (pos < CAP)
                            s_a[pos] = ((ekey & 0x1FFFu) << 18) | (0x3FFFFu - (unsigned)n);
                    }
                }
            }
        }
    }
    __syncthreads();

    // per-bucket rank sort (one wave per call)
    auto sort_bucket = [&](int bkt) {
        unsigned h = s_hist[bkt];
        if (h == 0u) return;
        unsigned end = s_start[bkt];        // post-scatter: sum_{j>=bkt} h[j]
        unsigned hi  = (end > CAP) ? CAP : end;
        unsigned lo  = (end >= h) ? end - h : 0u;
        if (lo > hi) lo = hi;
        unsigned sz = hi - lo;
        if (sz == 0u) return;
        if (sz <= 64u) {
            unsigned v = (l < (int)sz) ? s_a[lo + (unsigned)l] : 0u;
            int rank = 0;
            for (unsigned j = 0; j < sz; ++j)
                rank += ((unsigned)__shfl((int)v, (int)j) > v) ? 1 : 0;
            if (l < (int)sz) s_b[lo + (unsigned)rank] = v;
        } else {
            for (unsigned bb = 0; bb < sz; bb += 64u) {
                bool valid = bb + (unsigned)l < sz;
                unsigned v = valid ? s_a[lo + bb + (unsigned)l] : 0u;
                int rank = 0;
                for (unsigned j = 0; j < sz; ++j)
                    rank += (s_a[lo + j] > v) ? 1 : 0;
                if (valid) s_b[lo + (unsigned)rank] = v;
            }
        }
    };

    // ---- pre-sort group 0 (top 64 buckets) with all 16 waves ----
    for (int bkt = (1023 - 63) + w; bkt <= 1023; bkt += 16) sort_bucket(bkt);
    __syncthreads();

    // ---- Pipelined group loop: wave 0 greedy on g; waves 1-15 sort g+1 ----
    int count = 0;
    int nscat = 2;   // groups scattered so far (uniform)
    for (int g = 0; g < NGROUP; ++g) {
        const int BH = 1023 - (g << 6);
        const int BL = BH - 63;

        if (g >= nscat) {
            // RARE fallback: scatter all remaining buckets (< LAZY_BKT) from global
            for (int n4 = t; n4 < NQ4; n4 += 1024) {
                float4 s4 = *(const float4*)(obj + n4 * 4);
                float sv[4] = {s4.x, s4.y, s4.z, s4.w};
#pragma unroll
                for (int u = 0; u < 4; ++u) {
                    if (sv[u] >= SCORE_THR) {
                        unsigned ekey = score_key(sv[u]);
                        unsigned bkt  = ekey >> 13;
                        if (bkt > 1023u) bkt = 1023u;
                        if (bkt < LAZY_BKT) {
                            int n = n4 * 4 + u;
                            unsigned pos = atomicAdd(&s_start[bkt], 1u);
                            if (pos < CAP)
                                s_a[pos] = ((ekey & 0x1FFFu) << 18) | (0x3FFFFu - (unsigned)n);
                        }
                    }
                }
            }
            __syncthreads();
            nscat = NGROUP;
            for (int bkt = BL + w; bkt <= BH; bkt += 16) sort_bucket(bkt);
            __syncthreads();
        }

        if (w == 0) {
            unsigned glo = (g == 0) ? 0u : s_start[BH + 1];
            unsigned ghi = s_start[BL];
            if (glo > CAP) glo = CAP;
            if (ghi > CAP) ghi = CAP;

            if (glo < ghi && count < MAXDET) {
                // depth-4 software pipeline for box gathers (manual reg rotation)
                unsigned i0, i1, i2, i3;
                float4 q0, q1, q2, q3;
                auto loadc = [&](unsigned cb, unsigned& ix, float4& q) {
                    ix = 0u; q = make_float4(0.f, 0.f, 0.f, 0.f);
                    unsigned p0 = cb + (unsigned)l;
                    if (p0 < ghi) {
                        unsigned p = s_b[p0];
                        ix = 0x3FFFFu - (p & 0x3FFFFu);
                        q = *(const float4*)(bx + (size_t)ix * 4);
                    }
                };
                loadc(glo,        i0, q0);
                loadc(glo + 64u,  i1, q1);
                loadc(glo + 128u, i2, q2);
                loadc(glo + 192u, i3, q3);

                for (unsigned base = glo; base < ghi && count < MAXDET; base += 64u) {
                    unsigned cidx = i0; float4 cq = q0;
                    i0 = i1; q0 = q1;
                    i1 = i2; q1 = q2;
                    i2 = i3; q2 = q3;
                    loadc(base + 256u, i3, q3);

                    int m = (int)(ghi - base); if (m > 64) m = 64;
                    float cx1, cy1, cx2, cy2;
                    mk_corners(cq.x, cq.y, cq.z, cq.w, cx1, cy1, cx2, cy2);
                    float ca = areaf(cx1, cy1, cx2, cy2);

                    // vs-kept pre-filter: batches of 4 independent LDS loads
                    bool sup = (l >= m);
                    int k = 0;
                    for (; k + 4 <= count; k += 4) {
                        float4 kb0 = s_kbox[k],     kb1 = s_kbox[k + 1];
                        float4 kb2 = s_kbox[k + 2], kb3 = s_kbox[k + 3];
                        sup = sup | iou_gt(kb0.x, kb0.y, kb0.z, kb0.w,
                                           areaf(kb0.x, kb0.y, kb0.z, kb0.w), cx1, cy1, cx2, cy2, ca);
                        sup = sup | iou_gt(kb1.x, kb1.y, kb1.z, kb1.w,
                                           areaf(kb1.x, kb1.y, kb1.z, kb1.w), cx1, cy1, cx2, cy2, ca);
                        sup = sup | iou_gt(kb2.x, kb2.y, kb2.z, kb2.w,
                                           areaf(kb2.x, kb2.y, kb2.z, kb2.w), cx1, cy1, cx2, cy2, ca);
                        sup = sup | iou_gt(kb3.x, kb3.y, kb3.z, kb3.w,
                                           areaf(kb3.x, kb3.y, kb3.z, kb3.w), cx1, cy1, cx2, cy2, ca);
                    }
                    for (; k < count; ++k) {
                        float4 kb = s_kbox[k];
                        sup = sup | iou_gt(kb.x, kb.y, kb.z, kb.w,
                                           areaf(kb.x, kb.y, kb.z, kb.w), cx1, cy1, cx2, cy2, ca);
                    }
                    unsigned long long act = __ballot(!sup);

                    // serial accept loop: v_readlane broadcasts, writes deferred
                    unsigned long long accmask = 0ull;
                    const int cbase = count;
                    while (act != 0ull && count < MAXDET) {
                        int j = (int)__builtin_ctzll(act);
                        accmask |= 1ull << j;
                        float bx1 = readlane_f(cx1, j), by1 = readlane_f(cy1, j);
                        float bx2 = readlane_f(cx2, j), by2 = readlane_f(cy2, j);
                        float bar = readlane_f(ca, j);
                        bool su = iou_gt(bx1, by1, bx2, by2, bar, cx1, cy1, cx2, cy2, ca);
                        ++count;
                        act &= ~(1ull << j);
                        act &= ~__ballot(su);
                    }

                    // parallel deferred writeback; score gathered only on accept
                    if (accmask & (1ull << l)) {
                        int slot = cbase + (int)__popcll(accmask & ((1ull << l) - 1ull));
                        s_kbox[slot] = make_float4(cx1, cy1, cx2, cy2);
                        s_kept_idx[slot] = cidx;
                        float* ob = out + ((size_t)b * MAXDET + slot) * 4;
                        ob[0] = cx1; ob[1] = cy1; ob[2] = cx2; ob[3] = cy2;
                        out[NBATCH * MAXDET * 4 + b * MAXDET + slot] = obj[cidx];
                    }
                    __asm__ volatile("s_waitcnt lgkmcnt(0)" ::: "memory");
                }
            }
            if (l == 0) s_count = count;
        } else if (g + 1 < NGROUP && g + 1 < nscat) {
            // waves 1-15: sort next group's 64 buckets (already scattered)
            const int BH2 = BH - 64, BL2 = BH2 - 63;
            for (int bkt = BL2 + (w - 1); bkt <= BH2; bkt += 15) sort_bucket(bkt);
        }
        __syncthreads();
        if (s_count >= MAXDET) break;
    }

    // ---- Epilogue: gather class rows, zero only tails, write count ----
    const int cf = s_count;
    for (int e = t; e < MAXDET * 4; e += 1024) {
        if ((e >> 2) >= cf) out[(size_t)b * MAXDET * 4 + e] = 0.0f;
    }
    for (int i = t; i < MAXDET; i += 1024) {
        if (i >= cf) out[NBATCH * MAXDET * 4 + b * MAXDET + i] = 0.0f;
    }
    const float* cp = class_prob + (size_t)b * NBOX * NCLS;
    float* oc = out + NBATCH * MAXDET * 5 + (size_t)b * MAXDET * NCLS;
    for (int e = t; e < cf * NCLS; e += 1024) {
        int i = e / NCLS;
        int c = e - i * NCLS;
        oc[e] = cp[(size_t)s_kept_idx[i] * NCLS + c];
    }
    for (int e = t + cf * NCLS; e < MAXDET * NCLS; e += 1024) oc[e] = 0.0f;
    if (t == 0)
        out[NBATCH * MAXDET * 5 + NBATCH * MAXDET * NCLS + b] = (float)cf;
}

extern "C" void kernel_launch(void* const* d_in, const int* in_sizes, int n_in,
                              void* d_out, int out_size, void* d_ws, size_t ws_size,
                              hipStream_t stream) {
    const float* boxes = (const float*)d_in[0];
    const float* objn  = (const float*)d_in[1];
    const float* clsp  = (const float*)d_in[2];
    float* out = (float*)d_out;
    nms_kernel<<<dim3(NBATCH), dim3(1024), 0, stream>>>(boxes, objn, clsp, out);
}